// Round 3
// baseline (822.200 us; speedup 1.0000x reference)
//
#include <hip/hip_runtime.h>
#include <limits.h>

#define NUM_HEADS 32
#define HEAD_DIM 128
#define ROPE_DIM 64

// clang-native 4-float vector: required by __builtin_nontemporal_load/store
// (HIP's float4 is a struct and is rejected). Same 16B layout & codegen.
typedef float v4f __attribute__((ext_vector_type(4)));

// v3: grid-stride persistent form (m13 copy structure).
//  - 2048 blocks x 256 threads = 8 blocks/CU x 4 waves = 32 waves/CU (max occ).
//  - Each block processes 16 tokens; cu_seqlen is loaded ONCE per block into
//    lane registers, so the per-token segment lookup is pure ALU
//    (ballot + popcll + shfl) with zero memory ops on the critical path.
//  - Streaming in/out loads+stores are non-temporal (no L2 pollution; sin/cos
//    stay cached). Every input byte is read exactly once.
// Per token (one block-iteration, 256 threads):
//   rope region: 32 heads * 8 float4-pairs = 256 pairs, one per thread;
//   pass region: 32 heads * 16 float4 = 512 quads, two per thread.
__global__ __launch_bounds__(256) void ApplyRotary_27814208209209_kernel(
    const float* __restrict__ in,
    const float* __restrict__ sin_cache,
    const float* __restrict__ cos_cache,
    const int* __restrict__ cu_seqlen,
    int n_cu,            // number of entries in cu_seqlen (== segments + 1)
    int total_tokens,
    float* __restrict__ out)
{
    const int tid  = threadIdx.x;
    const int lane = tid & 63;

    // ---- cu_seqlen -> registers, once per block (n_cu = 17 here) ----
    const int cuv = (lane < n_cu) ? cu_seqlen[lane] : INT_MAX;

    // ---- per-thread static indices ----
    const int h = tid >> 3;                 // head 0..31
    const int p = tid & 7;                  // quad 0..7 -> dims [4p, 4p+3]
    const int ropeBase = h * (HEAD_DIM / 4);

    const int j0 = tid;                     // pass-through quads, 2/thread
    const int j1 = tid + 256;
    const int idx0 = (j0 >> 4) * (HEAD_DIM / 4) + (ROPE_DIM / 4) + (j0 & 15);
    const int idx1 = (j1 >> 4) * (HEAD_DIM / 4) + (ROPE_DIM / 4) + (j1 & 15);

    for (int t = blockIdx.x; t < total_tokens; t += gridDim.x) {
        const v4f* in4  = (const v4f*)(in  + (size_t)t * (NUM_HEADS * HEAD_DIM));
        v4f*       out4 = (v4f*)      (out + (size_t)t * (NUM_HEADS * HEAD_DIM));

        // issue all streaming loads first (independent of the lookup)
        const v4f a  = __builtin_nontemporal_load(&in4[ropeBase + p]);      // x1
        const v4f b  = __builtin_nontemporal_load(&in4[ropeBase + p + 8]);  // x2
        const v4f v0 = __builtin_nontemporal_load(&in4[idx0]);
        const v4f v1 = __builtin_nontemporal_load(&in4[idx1]);

        // register-resident segment lookup: seg = count(cu <= t) - 1
        const unsigned long long le = __ballot(cuv <= t);
        const int seg = __popcll(le) - 1;        // cu[0]=0 <= t, so seg >= 0
        const int off = t - __shfl(cuv, seg);

        const v4f* sin4 = (const v4f*)(sin_cache + (size_t)off * ROPE_DIM);
        const v4f* cos4 = (const v4f*)(cos_cache + (size_t)off * ROPE_DIM);
        const v4f s1 = sin4[p];
        const v4f c1 = cos4[p];
        const v4f s2 = sin4[p + 8];
        const v4f c2 = cos4[p + 8];

        v4f oa, ob;
        // out[d]    = -x2[d]*sin[d]    + x1[d]*cos[d]      (d in [0,32))
        oa.x = fmaf(-b.x, s1.x, a.x * c1.x);
        oa.y = fmaf(-b.y, s1.y, a.y * c1.y);
        oa.z = fmaf(-b.z, s1.z, a.z * c1.z);
        oa.w = fmaf(-b.w, s1.w, a.w * c1.w);
        // out[d+32] =  x1[d]*sin[d+32] + x2[d]*cos[d+32]
        ob.x = fmaf(a.x, s2.x, b.x * c2.x);
        ob.y = fmaf(a.y, s2.y, b.y * c2.y);
        ob.z = fmaf(a.z, s2.z, b.z * c2.z);
        ob.w = fmaf(a.w, s2.w, b.w * c2.w);

        __builtin_nontemporal_store(oa, &out4[ropeBase + p]);
        __builtin_nontemporal_store(ob, &out4[ropeBase + p + 8]);
        __builtin_nontemporal_store(v0, &out4[idx0]);
        __builtin_nontemporal_store(v1, &out4[idx1]);
    }
}

extern "C" void kernel_launch(void* const* d_in, const int* in_sizes, int n_in,
                              void* d_out, int out_size, void* d_ws, size_t ws_size,
                              hipStream_t stream) {
    const float* in        = (const float*)d_in[0];
    const float* sin_cache = (const float*)d_in[1];
    const float* cos_cache = (const float*)d_in[2];
    const int*   cu        = (const int*)d_in[3];
    const int    n_cu      = in_sizes[3];   // 17 entries for this problem

    const int total_tokens = in_sizes[0] / (NUM_HEADS * HEAD_DIM);

    int blocks = total_tokens < 2048 ? total_tokens : 2048;

    ApplyRotary_27814208209209_kernel<<<blocks, 256, 0, stream>>>(
        in, sin_cache, cos_cache, cu, n_cu, total_tokens, (float*)d_out);
}